// Round 1
// baseline (367.688 us; speedup 1.0000x reference)
//
#include <hip/hip_runtime.h>

typedef unsigned short u16;
typedef short bf16x8 __attribute__((ext_vector_type(8)));
typedef float f32x4 __attribute__((ext_vector_type(4)));

#define MFMA16(a, b, c) __builtin_amdgcn_mfma_f32_16x16x32_bf16((a), (b), (c), 0, 0, 0)

static __device__ __forceinline__ u16 f2bf(float f) {
    union { float f; unsigned int u; } v; v.f = f;
    unsigned int u = v.u;
    u += 0x7fffu + ((u >> 16) & 1u);   // round-to-nearest-even
    return (u16)(u >> 16);
}

// ---------------------------------------------------------------------------
// Prep: starts/counts via binary search (batch_indices sorted) + weights->bf16
// ---------------------------------------------------------------------------
__global__ void prep_kernel(const int* __restrict__ bidx, int N,
                            const float* __restrict__ w_in, const float* __restrict__ w_out,
                            int* __restrict__ starts, int* __restrict__ counts,
                            u16* __restrict__ w_in_bf, u16* __restrict__ w_out_bf) {
    int tid = blockIdx.x * blockDim.x + threadIdx.x;   // grid 192x256 = 49152
    if (tid < 1024) {
        int lo = 0, hi = N;
        while (lo < hi) { int mid = (lo + hi) >> 1; if (bidx[mid] < tid) lo = mid + 1; else hi = mid; }
        int s0 = lo;
        lo = 0; hi = N;
        int v1 = tid + 1;
        while (lo < hi) { int mid = (lo + hi) >> 1; if (bidx[mid] < v1) lo = mid + 1; else hi = mid; }
        starts[tid] = s0;
        counts[tid] = lo - s0;
    }
    {   // 49152 float4s of in_proj_w (768x256)
        float4 v = ((const float4*)w_in)[tid];
        ushort4 o; o.x = f2bf(v.x); o.y = f2bf(v.y); o.z = f2bf(v.z); o.w = f2bf(v.w);
        ((ushort4*)w_in_bf)[tid] = o;
    }
    if (tid < 16384) {  // float4s of out_proj_w (256x256)
        float4 v = ((const float4*)w_out)[tid];
        ushort4 o; o.x = f2bf(v.x); o.y = f2bf(v.y); o.z = f2bf(v.z); o.w = f2bf(v.w);
        ((ushort4*)w_out_bf)[tid] = o;
    }
}

// ---------------------------------------------------------------------------
// Fused graph-attention: one workgroup (4 waves) per graph, head-pair groups.
// Occupancy redesign vs round 0:
//   - QKV repartitioned: wave w owns query rows [16w,16w+16) for ALL 12 weight
//     tiles per group -> afr shrinks from 128 regs (4 st) to 32 regs (1 st).
//     W tiles are read 4x per block but live in L2 (FETCH_SIZE is HBM-only).
//   - cs ctx-staging buffer (33.8 KB) removed: per-head ctx strip round-trips
//     through the per-wave p_s scratch into actx[8] A-frag registers (same
//     lane mapping phase 4 used when reading cs).
//   - LDS 70656 -> 36864 B; __launch_bounds__(256,4) -> 4 blocks/CU,
//     16 waves/CU, all 1024 blocks co-resident in one round.
// ---------------------------------------------------------------------------
__global__ __launch_bounds__(256, 4) void gat_kernel(
    const float* __restrict__ X, const float* __restrict__ bias_in,
    const float* __restrict__ bias_out,
    const int* __restrict__ starts, const int* __restrict__ counts,
    const u16* __restrict__ w_in_bf, const u16* __restrict__ w_out_bf,
    float* __restrict__ out, float* __restrict__ wout) {

    __shared__ u16 qg[64][72];       // q for current head pair [node][dim0..63]
    __shared__ u16 kg[64][72];       // k for current head pair
    __shared__ u16 vt[64][72];       // v transposed [dim0..63][key]
    __shared__ u16 p_s[4][16][72];   // per-wave scratch: P transpose, then ctx transpose

    const int b = blockIdx.x;
    const int tid = threadIdx.x;
    const int w = tid >> 6;
    const int lane = tid & 63;
    const int n = lane & 15;        // MFMA col / B-row index
    const int quad = lane >> 4;     // MFMA quad
    const int s = starts[b];
    const int c = counts[b];
    const int m0 = w * 16;

    // ---- Phase 1: this wave's 16 X rows as A-frags (zero-pad rows >= c) ----
    bf16x8 afr[8];
    {
        int row = m0 + n;
        bool ok = row < c;
        const float* src = X + (long)(s + row) * 256 + quad * 8;
        #pragma unroll
        for (int ks = 0; ks < 8; ++ks) {
            float4 v0 = make_float4(0.f, 0.f, 0.f, 0.f);
            float4 v1 = make_float4(0.f, 0.f, 0.f, 0.f);
            if (ok) {
                v0 = *(const float4*)(src + ks * 32);
                v1 = *(const float4*)(src + ks * 32 + 4);
            }
            bf16x8 a;
            a[0] = (short)f2bf(v0.x); a[1] = (short)f2bf(v0.y);
            a[2] = (short)f2bf(v0.z); a[3] = (short)f2bf(v0.w);
            a[4] = (short)f2bf(v1.x); a[5] = (short)f2bf(v1.y);
            a[6] = (short)f2bf(v1.z); a[7] = (short)f2bf(v1.w);
            afr[ks] = a;
        }
    }

    const float scale = 0.17677669529663687f;  // 1/sqrt(32)
    float wacc[4][4];
    #pragma unroll
    for (int t = 0; t < 4; ++t)
        #pragma unroll
        for (int r = 0; r < 4; ++r) wacc[t][r] = 0.f;
    bf16x8 actx[8];                  // ctx A-frags, one per head, filled per group

    // ---- Phase 2+3: head-pair groups ----
    #pragma unroll 1
    for (int g = 0; g < 4; ++g) {
        // QKV for heads 2g,2g+1: each wave computes its 16 rows x all 12 tiles
        #pragma unroll 4
        for (int j = 0; j < 12; ++j) {
            const int type = j >> 2;            // 0=q, 1=k, 2=v
            const int sub = j & 3;              // 16-col chunk within the 64-dim pair
            const int wrow = type * 256 + g * 64 + sub * 16 + n;
            const u16* wr = w_in_bf + wrow * 256 + quad * 8;
            const float bias = bias_in[wrow];

            f32x4 acc = (f32x4){0.f, 0.f, 0.f, 0.f};
            #pragma unroll
            for (int kh = 0; kh < 2; ++kh) {    // split bfr in halves (reg pressure)
                bf16x8 bfr[4];
                #pragma unroll
                for (int k4 = 0; k4 < 4; ++k4) bfr[k4] = *(const bf16x8*)(wr + (kh * 4 + k4) * 32);
                #pragma unroll
                for (int k4 = 0; k4 < 4; ++k4) acc = MFMA16(afr[kh * 4 + k4], bfr[k4], acc);
            }

            if (type == 2) {                    // v: transposed, 4 keys packed
                ushort4 pk;
                pk.x = f2bf(acc[0] + bias); pk.y = f2bf(acc[1] + bias);
                pk.z = f2bf(acc[2] + bias); pk.w = f2bf(acc[3] + bias);
                *(ushort4*)&vt[sub * 16 + n][m0 + quad * 4] = pk;
            } else {                            // q/k: row-major
                u16 (*dst)[72] = type ? kg : qg;
                #pragma unroll
                for (int r = 0; r < 4; ++r)
                    dst[m0 + quad * 4 + r][sub * 16 + n] = f2bf(acc[r] + bias);
            }
        }
        __syncthreads();

        // attention for the 2 heads; wave w owns query rows [16w, 16w+16)
        #pragma unroll 1
        for (int hh = 0; hh < 2; ++hh) {
            bf16x8 aq = *(const bf16x8*)&qg[m0 + n][hh * 32 + quad * 8];
            f32x4 sc[4];
            #pragma unroll
            for (int t = 0; t < 4; ++t) {
                bf16x8 bk = *(const bf16x8*)&kg[t * 16 + n][hh * 32 + quad * 8];
                f32x4 z = (f32x4){0.f, 0.f, 0.f, 0.f};
                sc[t] = MFMA16(aq, bk, z);
            }
            float p[4][4], inv[4];
            #pragma unroll
            for (int r = 0; r < 4; ++r) {
                float mx = -1e30f;
                #pragma unroll
                for (int t = 0; t < 4; ++t) {
                    float sv = ((t * 16 + n) < c) ? sc[t][r] * scale : -1e30f;
                    p[t][r] = sv;
                    mx = fmaxf(mx, sv);
                }
                #pragma unroll
                for (int d = 1; d < 16; d <<= 1) mx = fmaxf(mx, __shfl_xor(mx, d, 64));
                float sm = 0.f;
                #pragma unroll
                for (int t = 0; t < 4; ++t) {
                    float e = ((t * 16 + n) < c) ? __expf(p[t][r] - mx) : 0.f;
                    p[t][r] = e; sm += e;
                }
                #pragma unroll
                for (int d = 1; d < 16; d <<= 1) sm += __shfl_xor(sm, d, 64);
                inv[r] = 1.f / sm;
                #pragma unroll
                for (int t = 0; t < 4; ++t) wacc[t][r] += p[t][r] * (inv[r] * 0.125f);
            }
            // P: C-layout -> A-layout via wave-private LDS (in-wave ordering)
            #pragma unroll
            for (int t = 0; t < 4; ++t)
                #pragma unroll
                for (int r = 0; r < 4; ++r)
                    p_s[w][quad * 4 + r][t * 16 + n] = f2bf(p[t][r]);
            // ctx strip = P.V: hold BOTH nt accumulators before touching p_s again
            f32x4 c0 = (f32x4){0.f, 0.f, 0.f, 0.f};
            f32x4 c1 = (f32x4){0.f, 0.f, 0.f, 0.f};
            #pragma unroll
            for (int k2 = 0; k2 < 2; ++k2) {
                bf16x8 ap  = *(const bf16x8*)&p_s[w][n][k2 * 32 + quad * 8];
                bf16x8 bv0 = *(const bf16x8*)&vt[hh * 32 + n][k2 * 32 + quad * 8];
                bf16x8 bv1 = *(const bf16x8*)&vt[hh * 32 + 16 + n][k2 * 32 + quad * 8];
                c0 = MFMA16(ap, bv0, c0);
                c1 = MFMA16(ap, bv1, c1);
            }
            // normalized ctx strip (16 queries x 32 dims) -> p_s (P dead now),
            // read back as the A-frag phase 4 needs (same mapping old cs had)
            #pragma unroll
            for (int r = 0; r < 4; ++r) {
                p_s[w][quad * 4 + r][n]      = f2bf(c0[r] * inv[r]);
                p_s[w][quad * 4 + r][16 + n] = f2bf(c1[r] * inv[r]);
            }
            actx[g * 2 + hh] = *(const bf16x8*)&p_s[w][n][quad * 8];
        }
        __syncthreads();   // before next group overwrites qg/kg/vt
    }

    // weights output: head-mean attn [B,64,64]
    #pragma unroll
    for (int t = 0; t < 4; ++t)
        #pragma unroll
        for (int r = 0; r < 4; ++r)
            wout[b * 4096 + (m0 + quad * 4 + r) * 64 + t * 16 + n] = wacc[t][r];

    // ---- Phase 4: out = ctx @ W_out^T + b_out, written [L, B, E] ----
    #pragma unroll 2
    for (int ct = 0; ct < 16; ++ct) {
        bf16x8 bfr[8];
        const u16* wr = w_out_bf + (ct * 16 + n) * 256 + quad * 8;
        #pragma unroll
        for (int ks = 0; ks < 8; ++ks) bfr[ks] = *(const bf16x8*)(wr + ks * 32);
        f32x4 acc = (f32x4){0.f, 0.f, 0.f, 0.f};
        #pragma unroll
        for (int ks = 0; ks < 8; ++ks) acc = MFMA16(actx[ks], bfr[ks], acc);
        float bias = bias_out[ct * 16 + n];
        #pragma unroll
        for (int r = 0; r < 4; ++r)
            out[(m0 + quad * 4 + r) * 262144 + b * 256 + ct * 16 + n] = acc[r] + bias;
    }
}

// ---------------------------------------------------------------------------
extern "C" void kernel_launch(void* const* d_in, const int* in_sizes, int n_in,
                              void* d_out, int out_size, void* d_ws, size_t ws_size,
                              hipStream_t stream) {
    const float* X     = (const float*)d_in[0];
    const int*   bidx  = (const int*)d_in[1];
    const float* w_in  = (const float*)d_in[2];
    const float* b_in  = (const float*)d_in[3];
    const float* w_out = (const float*)d_in[4];
    const float* b_out = (const float*)d_in[5];
    const int N = in_sizes[1];

    float* out  = (float*)d_out;                 // [64, 1024, 256]
    float* wout = out + 64 * 1024 * 256;         // [1024, 64, 64]

    int* starts   = (int*)d_ws;
    int* counts   = starts + 1024;
    u16* w_in_bf  = (u16*)(counts + 1024);       // 768x256 bf16
    u16* w_out_bf = w_in_bf + 196608;            // 256x256 bf16

    hipLaunchKernelGGL(prep_kernel, dim3(192), dim3(256), 0, stream,
                       bidx, N, w_in, w_out, starts, counts, w_in_bf, w_out_bf);
    hipLaunchKernelGGL(gat_kernel, dim3(1024), dim3(256), 0, stream,
                       X, b_in, b_out, starts, counts, w_in_bf, w_out_bf, out, wout);
}

// Round 2
// 293.663 us; speedup vs baseline: 1.2521x; 1.2521x over previous
//
#include <hip/hip_runtime.h>

typedef unsigned short u16;
typedef short bf16x8 __attribute__((ext_vector_type(8)));
typedef float f32x4 __attribute__((ext_vector_type(4)));

#define MFMA16(a, b, c) __builtin_amdgcn_mfma_f32_16x16x32_bf16((a), (b), (c), 0, 0, 0)

static __device__ __forceinline__ u16 f2bf(float f) {
    union { float f; unsigned int u; } v; v.f = f;
    unsigned int u = v.u;
    u += 0x7fffu + ((u >> 16) & 1u);   // round-to-nearest-even
    return (u16)(u >> 16);
}

// ---------------------------------------------------------------------------
// Prep: starts/counts via binary search (batch_indices sorted) + weights->bf16
// ---------------------------------------------------------------------------
__global__ void prep_kernel(const int* __restrict__ bidx, int N,
                            const float* __restrict__ w_in, const float* __restrict__ w_out,
                            int* __restrict__ starts, int* __restrict__ counts,
                            u16* __restrict__ w_in_bf, u16* __restrict__ w_out_bf) {
    int tid = blockIdx.x * blockDim.x + threadIdx.x;   // grid 192x256 = 49152
    if (tid < 1024) {
        int lo = 0, hi = N;
        while (lo < hi) { int mid = (lo + hi) >> 1; if (bidx[mid] < tid) lo = mid + 1; else hi = mid; }
        int s0 = lo;
        lo = 0; hi = N;
        int v1 = tid + 1;
        while (lo < hi) { int mid = (lo + hi) >> 1; if (bidx[mid] < v1) lo = mid + 1; else hi = mid; }
        starts[tid] = s0;
        counts[tid] = lo - s0;
    }
    {   // 49152 float4s of in_proj_w (768x256)
        float4 v = ((const float4*)w_in)[tid];
        ushort4 o; o.x = f2bf(v.x); o.y = f2bf(v.y); o.z = f2bf(v.z); o.w = f2bf(v.w);
        ((ushort4*)w_in_bf)[tid] = o;
    }
    if (tid < 16384) {  // float4s of out_proj_w (256x256)
        float4 v = ((const float4*)w_out)[tid];
        ushort4 o; o.x = f2bf(v.x); o.y = f2bf(v.y); o.z = f2bf(v.z); o.w = f2bf(v.w);
        ((ushort4*)w_out_bf)[tid] = o;
    }
}

// ---------------------------------------------------------------------------
// Fused graph-attention v2: one workgroup = 8 waves (512 thr) per graph.
//   - QKV: wave (wh = w>>2, wj = w&3) owns M-half wh (st in {2wh, 2wh+1}) and
//     tiles j in {wj, wj+4, wj+8}. afr[2][8] = 64 VGPR (vs 128 in round 0),
//     each B-tile loaded by 2 waves only, MFMA:load = 2:1.
//   - Attention: wave (hh = w&1, rt = w>>1) does ONE (head, 16-row) unit
//     per group -> serial softmax chain per wave halves vs round 0.
//   - Phase 4: wave (sp = w&1, cq = w>>1) does st-pair x ct-quarter with
//     ctx A-frags from cs LDS; each W_out tile loaded by 2 waves.
//   - LDS 78 KB -> 2 blocks/CU; launch_bounds(512,2) caps VGPR at 128
//     -> 16 waves/CU with round-0-grade per-wave efficiency.
// ---------------------------------------------------------------------------
__global__ __launch_bounds__(512, 2) void gat_kernel(
    const float* __restrict__ X, const float* __restrict__ bias_in,
    const float* __restrict__ bias_out,
    const int* __restrict__ starts, const int* __restrict__ counts,
    const u16* __restrict__ w_in_bf, const u16* __restrict__ w_out_bf,
    float* __restrict__ out, float* __restrict__ wout) {

    __shared__ u16 qg[64][72];       // q for current head pair [node][dim0..63]
    __shared__ u16 kg[64][72];       // k for current head pair
    __shared__ u16 vt[64][72];       // v transposed [dim0..63][key]
    __shared__ u16 p_s[8][16][72];   // per-wave P scratch; reused as f32 wout staging
    __shared__ u16 cs[64][264];      // ctx staging [node][all 256 dims], persists

    const int b = blockIdx.x;
    const int tid = threadIdx.x;
    const int w = tid >> 6;          // 0..7
    const int lane = tid & 63;
    const int n = lane & 15;         // MFMA col / B-row index
    const int quad = lane >> 4;      // MFMA quad
    const int s = starts[b];
    const int c = counts[b];

    const int wh = w >> 2;           // QKV M-half
    const int wj = w & 3;            // QKV tile set
    const int hh = w & 1;            // attn head-in-pair
    const int rt = w >> 1;           // attn row-tile
    const int m0 = rt * 16;

    // ---- Phase 1: this wave's 32 X rows (2 st) as A-frags (zero-pad >= c) ----
    bf16x8 afr[2][8];
    #pragma unroll
    for (int st2 = 0; st2 < 2; ++st2) {
        int row = wh * 32 + st2 * 16 + n;
        bool ok = row < c;
        const float* src = X + (long)(s + row) * 256 + quad * 8;
        #pragma unroll
        for (int ks = 0; ks < 8; ++ks) {
            float4 v0 = make_float4(0.f, 0.f, 0.f, 0.f);
            float4 v1 = make_float4(0.f, 0.f, 0.f, 0.f);
            if (ok) {
                v0 = *(const float4*)(src + ks * 32);
                v1 = *(const float4*)(src + ks * 32 + 4);
            }
            bf16x8 a;
            a[0] = (short)f2bf(v0.x); a[1] = (short)f2bf(v0.y);
            a[2] = (short)f2bf(v0.z); a[3] = (short)f2bf(v0.w);
            a[4] = (short)f2bf(v1.x); a[5] = (short)f2bf(v1.y);
            a[6] = (short)f2bf(v1.z); a[7] = (short)f2bf(v1.w);
            afr[st2][ks] = a;
        }
    }

    const float scale = 0.17677669529663687f;  // 1/sqrt(32)
    float wacc[4][4];
    #pragma unroll
    for (int t = 0; t < 4; ++t)
        #pragma unroll
        for (int r = 0; r < 4; ++r) wacc[t][r] = 0.f;

    // ---- Phase 2+3: head-pair groups ----
    #pragma unroll 1
    for (int g = 0; g < 4; ++g) {
        // QKV: tiles j = wj + 4*i  (type = i since wj < 4), for 2 st each
        #pragma unroll
        for (int i = 0; i < 3; ++i) {
            const int wrow = i * 256 + g * 64 + wj * 16 + n;
            const u16* wr = w_in_bf + wrow * 256 + quad * 8;
            const float bias = bias_in[wrow];

            f32x4 acc[2];
            acc[0] = (f32x4){0.f, 0.f, 0.f, 0.f};
            acc[1] = (f32x4){0.f, 0.f, 0.f, 0.f};
            #pragma unroll
            for (int kh = 0; kh < 2; ++kh) {    // bfr halves (reg pressure)
                bf16x8 bfr[4];
                #pragma unroll
                for (int k4 = 0; k4 < 4; ++k4) bfr[k4] = *(const bf16x8*)(wr + (kh * 4 + k4) * 32);
                #pragma unroll
                for (int k4 = 0; k4 < 4; ++k4) {
                    acc[0] = MFMA16(afr[0][kh * 4 + k4], bfr[k4], acc[0]);
                    acc[1] = MFMA16(afr[1][kh * 4 + k4], bfr[k4], acc[1]);
                }
            }

            #pragma unroll
            for (int st2 = 0; st2 < 2; ++st2) {
                const int st = 2 * wh + st2;
                if (i == 2) {                      // v: transposed, 4 keys packed
                    ushort4 pk;
                    pk.x = f2bf(acc[st2][0] + bias); pk.y = f2bf(acc[st2][1] + bias);
                    pk.z = f2bf(acc[st2][2] + bias); pk.w = f2bf(acc[st2][3] + bias);
                    *(ushort4*)&vt[wj * 16 + n][st * 16 + quad * 4] = pk;
                } else {                           // q/k: row-major
                    u16 (*dst)[72] = i ? kg : qg;
                    #pragma unroll
                    for (int r = 0; r < 4; ++r)
                        dst[st * 16 + quad * 4 + r][wj * 16 + n] = f2bf(acc[st2][r] + bias);
                }
            }
        }
        __syncthreads();

        // attention: wave (hh, rt) does head g*2+hh for query rows [m0, m0+16)
        {
            const int h = g * 2 + hh;
            bf16x8 aq = *(const bf16x8*)&qg[m0 + n][hh * 32 + quad * 8];
            f32x4 sc[4];
            #pragma unroll
            for (int t = 0; t < 4; ++t) {
                bf16x8 bk = *(const bf16x8*)&kg[t * 16 + n][hh * 32 + quad * 8];
                f32x4 z = (f32x4){0.f, 0.f, 0.f, 0.f};
                sc[t] = MFMA16(aq, bk, z);
            }
            float p[4][4], inv[4];
            #pragma unroll
            for (int r = 0; r < 4; ++r) {
                float mx = -1e30f;
                #pragma unroll
                for (int t = 0; t < 4; ++t) {
                    float sv = ((t * 16 + n) < c) ? sc[t][r] * scale : -1e30f;
                    p[t][r] = sv;
                    mx = fmaxf(mx, sv);
                }
                #pragma unroll
                for (int d = 1; d < 16; d <<= 1) mx = fmaxf(mx, __shfl_xor(mx, d, 64));
                float sm = 0.f;
                #pragma unroll
                for (int t = 0; t < 4; ++t) {
                    float e = ((t * 16 + n) < c) ? __expf(p[t][r] - mx) : 0.f;
                    p[t][r] = e; sm += e;
                }
                #pragma unroll
                for (int d = 1; d < 16; d <<= 1) sm += __shfl_xor(sm, d, 64);
                inv[r] = 1.f / sm;
                #pragma unroll
                for (int t = 0; t < 4; ++t) wacc[t][r] += p[t][r] * (inv[r] * 0.125f);
            }
            // P: C-layout -> A-layout via wave-private LDS slot
            #pragma unroll
            for (int t = 0; t < 4; ++t)
                #pragma unroll
                for (int r = 0; r < 4; ++r)
                    p_s[w][quad * 4 + r][t * 16 + n] = f2bf(p[t][r]);
            // ctx strip = P.V, normalized, into cs (full 256-dim staging)
            #pragma unroll
            for (int nt = 0; nt < 2; ++nt) {
                f32x4 acc = (f32x4){0.f, 0.f, 0.f, 0.f};
                #pragma unroll
                for (int k2 = 0; k2 < 2; ++k2) {
                    bf16x8 ap = *(const bf16x8*)&p_s[w][n][k2 * 32 + quad * 8];
                    bf16x8 bv = *(const bf16x8*)&vt[hh * 32 + nt * 16 + n][k2 * 32 + quad * 8];
                    acc = MFMA16(ap, bv, acc);
                }
                #pragma unroll
                for (int r = 0; r < 4; ++r)
                    cs[m0 + quad * 4 + r][h * 32 + nt * 16 + n] = f2bf(acc[r] * inv[r]);
            }
        }
        __syncthreads();   // before next group overwrites qg/kg/vt; covers cs for phase 4
    }

    // ---- weights output: head-mean attn [B,64,64], pair-sum across hh ----
    // even wave (hh=0) stages its 4-head sum in p_s (f32), odd wave adds+stores
    {
        float* pw = (float*)&p_s[w & ~1][0][0];   // slots {2rt, 2rt+1} = 4608 B >= 4 KB
        if (hh == 0) {
            #pragma unroll
            for (int t = 0; t < 4; ++t)
                #pragma unroll
                for (int r = 0; r < 4; ++r)
                    pw[(quad * 4 + r) * 64 + t * 16 + n] = wacc[t][r];
        }
        __syncthreads();
        if (hh == 1) {
            #pragma unroll
            for (int t = 0; t < 4; ++t)
                #pragma unroll
                for (int r = 0; r < 4; ++r)
                    wout[b * 4096 + (m0 + quad * 4 + r) * 64 + t * 16 + n] =
                        wacc[t][r] + pw[(quad * 4 + r) * 64 + t * 16 + n];
        }
    }

    // ---- Phase 4: out = ctx @ W_out^T + b_out, written [L, B, E] ----
    // wave (sp = w&1, cq = w>>1): st in {2sp, 2sp+1}, ct in {4cq .. 4cq+3}
    {
        const int sp = w & 1;
        const int cq = w >> 1;
        bf16x8 actx[2][8];                        // afr dead -> regs reused
        #pragma unroll
        for (int st2 = 0; st2 < 2; ++st2)
            #pragma unroll
            for (int ks = 0; ks < 8; ++ks)
                actx[st2][ks] = *(const bf16x8*)&cs[(2 * sp + st2) * 16 + n][ks * 32 + quad * 8];

        #pragma unroll 2
        for (int ci = 0; ci < 4; ++ci) {
            const int ct = 4 * cq + ci;
            const u16* wr = w_out_bf + (ct * 16 + n) * 256 + quad * 8;
            f32x4 acc[2];
            acc[0] = (f32x4){0.f, 0.f, 0.f, 0.f};
            acc[1] = (f32x4){0.f, 0.f, 0.f, 0.f};
            #pragma unroll
            for (int kh = 0; kh < 2; ++kh) {
                bf16x8 bfr[4];
                #pragma unroll
                for (int k4 = 0; k4 < 4; ++k4) bfr[k4] = *(const bf16x8*)(wr + (kh * 4 + k4) * 32);
                #pragma unroll
                for (int k4 = 0; k4 < 4; ++k4) {
                    acc[0] = MFMA16(actx[0][kh * 4 + k4], bfr[k4], acc[0]);
                    acc[1] = MFMA16(actx[1][kh * 4 + k4], bfr[k4], acc[1]);
                }
            }
            float bias = bias_out[ct * 16 + n];
            #pragma unroll
            for (int st2 = 0; st2 < 2; ++st2) {
                const int orow = (2 * sp + st2) * 16 + quad * 4;
                #pragma unroll
                for (int r = 0; r < 4; ++r)
                    out[(orow + r) * 262144 + b * 256 + ct * 16 + n] = acc[st2][r] + bias;
            }
        }
    }
}

// ---------------------------------------------------------------------------
extern "C" void kernel_launch(void* const* d_in, const int* in_sizes, int n_in,
                              void* d_out, int out_size, void* d_ws, size_t ws_size,
                              hipStream_t stream) {
    const float* X     = (const float*)d_in[0];
    const int*   bidx  = (const int*)d_in[1];
    const float* w_in  = (const float*)d_in[2];
    const float* b_in  = (const float*)d_in[3];
    const float* w_out = (const float*)d_in[4];
    const float* b_out = (const float*)d_in[5];
    const int N = in_sizes[1];

    float* out  = (float*)d_out;                 // [64, 1024, 256]
    float* wout = out + 64 * 1024 * 256;         // [1024, 64, 64]

    int* starts   = (int*)d_ws;
    int* counts   = starts + 1024;
    u16* w_in_bf  = (u16*)(counts + 1024);       // 768x256 bf16
    u16* w_out_bf = w_in_bf + 196608;            // 256x256 bf16

    hipLaunchKernelGGL(prep_kernel, dim3(192), dim3(256), 0, stream,
                       bidx, N, w_in, w_out, starts, counts, w_in_bf, w_out_bf);
    hipLaunchKernelGGL(gat_kernel, dim3(1024), dim3(512), 0, stream,
                       X, b_in, b_out, starts, counts, w_in_bf, w_out_bf, out, wout);
}

// Round 4
// 287.997 us; speedup vs baseline: 1.2767x; 1.0197x over previous
//
#include <hip/hip_runtime.h>

typedef unsigned short u16;
typedef short bf16x8 __attribute__((ext_vector_type(8)));
typedef float f32x4 __attribute__((ext_vector_type(4)));

#define MFMA16(a, b, c) __builtin_amdgcn_mfma_f32_16x16x32_bf16((a), (b), (c), 0, 0, 0)

static __device__ __forceinline__ u16 f2bf(float f) {
    union { float f; unsigned int u; } v; v.f = f;
    unsigned int u = v.u;
    u += 0x7fffu + ((u >> 16) & 1u);   // round-to-nearest-even
    return (u16)(u >> 16);
}

// ---------------------------------------------------------------------------
// Prep: starts/counts via binary search (batch_indices sorted) + weights->bf16
// ---------------------------------------------------------------------------
__global__ void prep_kernel(const int* __restrict__ bidx, int N,
                            const float* __restrict__ w_in, const float* __restrict__ w_out,
                            int* __restrict__ starts, int* __restrict__ counts,
                            u16* __restrict__ w_in_bf, u16* __restrict__ w_out_bf) {
    int tid = blockIdx.x * blockDim.x + threadIdx.x;   // grid 192x256 = 49152
    if (tid < 1024) {
        int lo = 0, hi = N;
        while (lo < hi) { int mid = (lo + hi) >> 1; if (bidx[mid] < tid) lo = mid + 1; else hi = mid; }
        int s0 = lo;
        lo = 0; hi = N;
        int v1 = tid + 1;
        while (lo < hi) { int mid = (lo + hi) >> 1; if (bidx[mid] < v1) lo = mid + 1; else hi = mid; }
        starts[tid] = s0;
        counts[tid] = lo - s0;
    }
    {   // 49152 float4s of in_proj_w (768x256)
        float4 v = ((const float4*)w_in)[tid];
        ushort4 o; o.x = f2bf(v.x); o.y = f2bf(v.y); o.z = f2bf(v.z); o.w = f2bf(v.w);
        ((ushort4*)w_in_bf)[tid] = o;
    }
    if (tid < 16384) {  // float4s of out_proj_w (256x256)
        float4 v = ((const float4*)w_out)[tid];
        ushort4 o; o.x = f2bf(v.x); o.y = f2bf(v.y); o.z = f2bf(v.z); o.w = f2bf(v.w);
        ((ushort4*)w_out_bf)[tid] = o;
    }
}

// ---------------------------------------------------------------------------
// Fused graph-attention v4: 8 waves (512 thr) per graph.
// vs v3 (which FAILED): swapped QK^T gives C[key][query]; each lane holds 16
// of the 64 keys for its query (keys t*16 + quad*4 + r); the other 48 are in
// lanes lane^16/lane^32. v3 forgot the cross-quad reduction -> P summed to 4.
// Fix: 2-shuffle (d=16,32) max-reduce BEFORE exp, 2-shuffle sum-reduce after.
// Chain: 4 shuffles total vs 32 in the pre-swap version.
// Also: __launch_bounds__(512,4) -> 128-reg cap -> 2 blocks/CU (16 waves/CU).
// ---------------------------------------------------------------------------
__global__ __launch_bounds__(512, 4) void gat_kernel(
    const float* __restrict__ X, const float* __restrict__ bias_in,
    const float* __restrict__ bias_out,
    const int* __restrict__ starts, const int* __restrict__ counts,
    const u16* __restrict__ w_in_bf, const u16* __restrict__ w_out_bf,
    float* __restrict__ out, float* __restrict__ wout) {

    __shared__ u16 qg[64][72];       // q for current head pair [node][dim0..63]
    __shared__ u16 kg[64][72];       // k for current head pair
    __shared__ u16 vt[64][72];       // v transposed [dim0..63][key]
    __shared__ u16 p_s[8][16][72];   // per-wave P scratch; reused as f32 wout staging
    __shared__ u16 cs[64][256];      // ctx staging [node][all 256 dims], persists

    const int b = blockIdx.x;
    const int tid = threadIdx.x;
    const int w = tid >> 6;          // 0..7
    const int lane = tid & 63;
    const int n = lane & 15;         // MFMA col / B-row index
    const int quad = lane >> 4;      // MFMA quad
    const int s = starts[b];
    const int c = counts[b];

    const int wh = w >> 2;           // QKV M-half
    const int wj = w & 3;            // QKV tile set
    const int hh = w & 1;            // attn head-in-pair
    const int rt = w >> 1;           // attn row-tile
    const int m0 = rt * 16;

    // ---- Phase 1: this wave's 32 X rows (2 st) as A-frags (zero-pad >= c) ----
    bf16x8 afr[2][8];
    #pragma unroll
    for (int st2 = 0; st2 < 2; ++st2) {
        int row = wh * 32 + st2 * 16 + n;
        bool ok = row < c;
        const float* src = X + (long)(s + row) * 256 + quad * 8;
        #pragma unroll
        for (int ks = 0; ks < 8; ++ks) {
            float4 v0 = make_float4(0.f, 0.f, 0.f, 0.f);
            float4 v1 = make_float4(0.f, 0.f, 0.f, 0.f);
            if (ok) {
                v0 = *(const float4*)(src + ks * 32);
                v1 = *(const float4*)(src + ks * 32 + 4);
            }
            bf16x8 a;
            a[0] = (short)f2bf(v0.x); a[1] = (short)f2bf(v0.y);
            a[2] = (short)f2bf(v0.z); a[3] = (short)f2bf(v0.w);
            a[4] = (short)f2bf(v1.x); a[5] = (short)f2bf(v1.y);
            a[6] = (short)f2bf(v1.z); a[7] = (short)f2bf(v1.w);
            afr[st2][ks] = a;
        }
    }

    const float scale = 0.17677669529663687f;  // 1/sqrt(32)
    float wacc[4][4];                // head-mean acc, key = t*16+quad*4+r, query = m0+n
    #pragma unroll
    for (int t = 0; t < 4; ++t)
        #pragma unroll
        for (int r = 0; r < 4; ++r) wacc[t][r] = 0.f;

    // ---- Phase 2+3: head-pair groups ----
    #pragma unroll 1
    for (int g = 0; g < 4; ++g) {
        // QKV: tiles j = wj + 4*i  (type = i since wj < 4), for 2 st each
        #pragma unroll 1
        for (int i = 0; i < 3; ++i) {
            const int wrow = i * 256 + g * 64 + wj * 16 + n;
            const u16* wr = w_in_bf + wrow * 256 + quad * 8;
            const float bias = bias_in[wrow];

            f32x4 acc[2];
            acc[0] = (f32x4){0.f, 0.f, 0.f, 0.f};
            acc[1] = (f32x4){0.f, 0.f, 0.f, 0.f};
            #pragma unroll
            for (int kh = 0; kh < 2; ++kh) {    // bfr halves (reg pressure)
                bf16x8 bfr[4];
                #pragma unroll
                for (int k4 = 0; k4 < 4; ++k4) bfr[k4] = *(const bf16x8*)(wr + (kh * 4 + k4) * 32);
                #pragma unroll
                for (int k4 = 0; k4 < 4; ++k4) {
                    acc[0] = MFMA16(afr[0][kh * 4 + k4], bfr[k4], acc[0]);
                    acc[1] = MFMA16(afr[1][kh * 4 + k4], bfr[k4], acc[1]);
                }
            }

            #pragma unroll
            for (int st2 = 0; st2 < 2; ++st2) {
                const int st = 2 * wh + st2;
                if (i == 2) {                      // v: transposed, 4 keys packed
                    ushort4 pk;
                    pk.x = f2bf(acc[st2][0] + bias); pk.y = f2bf(acc[st2][1] + bias);
                    pk.z = f2bf(acc[st2][2] + bias); pk.w = f2bf(acc[st2][3] + bias);
                    *(ushort4*)&vt[wj * 16 + n][st * 16 + quad * 4] = pk;
                } else {                           // q/k: row-major
                    u16 (*dst)[72] = i ? kg : qg;
                    #pragma unroll
                    for (int r = 0; r < 4; ++r)
                        dst[st * 16 + quad * 4 + r][wj * 16 + n] = f2bf(acc[st2][r] + bias);
                }
            }
        }
        __syncthreads();

        // attention: wave (hh, rt) does head g*2+hh for query rows [m0, m0+16)
        // SWAPPED: C[key][query]; lane (n,quad) holds query m0+n, keys
        // t*16+quad*4+r. Full key set for a query spans lanes {n, n^16, n^32, n^48}
        // -> cross-quad reduce via __shfl_xor d=16,32 (2 ops each).
        {
            const int h = g * 2 + hh;
            bf16x8 aq = *(const bf16x8*)&qg[m0 + n][hh * 32 + quad * 8];
            f32x4 sc[4];
            #pragma unroll
            for (int t = 0; t < 4; ++t) {
                bf16x8 bk = *(const bf16x8*)&kg[t * 16 + n][hh * 32 + quad * 8];
                f32x4 z = (f32x4){0.f, 0.f, 0.f, 0.f};
                sc[t] = MFMA16(bk, aq, z);         // A=K tile, B=Q -> C[key][query]
            }
            float pv[4][4];
            float mx = -1e30f;
            #pragma unroll
            for (int t = 0; t < 4; ++t)
                #pragma unroll
                for (int r = 0; r < 4; ++r) {
                    float sv = ((t * 16 + quad * 4 + r) < c) ? sc[t][r] * scale : -1e30f;
                    pv[t][r] = sv;
                    mx = fmaxf(mx, sv);
                }
            mx = fmaxf(mx, __shfl_xor(mx, 16, 64));   // cross-quad max (BEFORE exp)
            mx = fmaxf(mx, __shfl_xor(mx, 32, 64));
            float sm = 0.f;
            #pragma unroll
            for (int t = 0; t < 4; ++t)
                #pragma unroll
                for (int r = 0; r < 4; ++r) {
                    float e = ((t * 16 + quad * 4 + r) < c) ? __expf(pv[t][r] - mx) : 0.f;
                    pv[t][r] = e; sm += e;
                }
            sm += __shfl_xor(sm, 16, 64);             // cross-quad sum
            sm += __shfl_xor(sm, 32, 64);
            float invs = 1.f / sm;                    // per-query scalar
            #pragma unroll
            for (int t = 0; t < 4; ++t)
                #pragma unroll
                for (int r = 0; r < 4; ++r) {
                    pv[t][r] *= invs;                 // pre-normalized P
                    wacc[t][r] += pv[t][r] * 0.125f;
                }
            // P^ -> p_s[query][key] (A-layout for PV), 4 ushort4 writes
            #pragma unroll
            for (int t = 0; t < 4; ++t) {
                ushort4 pk;
                pk.x = f2bf(pv[t][0]); pk.y = f2bf(pv[t][1]);
                pk.z = f2bf(pv[t][2]); pk.w = f2bf(pv[t][3]);
                *(ushort4*)&p_s[w][n][t * 16 + quad * 4] = pk;
            }
            // ctx strip = P^.V (already normalized) into cs
            #pragma unroll
            for (int nt = 0; nt < 2; ++nt) {
                f32x4 acc = (f32x4){0.f, 0.f, 0.f, 0.f};
                #pragma unroll
                for (int k2 = 0; k2 < 2; ++k2) {
                    bf16x8 ap = *(const bf16x8*)&p_s[w][n][k2 * 32 + quad * 8];
                    bf16x8 bv = *(const bf16x8*)&vt[hh * 32 + nt * 16 + n][k2 * 32 + quad * 8];
                    acc = MFMA16(ap, bv, acc);
                }
                #pragma unroll
                for (int r = 0; r < 4; ++r)
                    cs[m0 + quad * 4 + r][h * 32 + nt * 16 + n] = f2bf(acc[r]);
            }
        }
        __syncthreads();   // before next group overwrites qg/kg/vt; covers cs for phase 4
    }

    // ---- weights output: head-mean attn [B,64,64], pair-sum across hh ----
    // wacc: key = t*16+quad*4+r for query m0+n. even wave stages f32, odd adds+stores.
    {
        float* pw = (float*)&p_s[w & ~1][0][0];   // two wave slots = 4608 B; stride 72 floats
        if (hh == 0) {
            #pragma unroll
            for (int t = 0; t < 4; ++t) {
                float4 f4 = make_float4(wacc[t][0], wacc[t][1], wacc[t][2], wacc[t][3]);
                *(float4*)&pw[n * 72 + t * 16 + quad * 4] = f4;
            }
        }
        __syncthreads();
        if (hh == 1) {
            #pragma unroll
            for (int t = 0; t < 4; ++t) {
                float4 f4 = *(const float4*)&pw[n * 72 + t * 16 + quad * 4];
                float4 o;
                o.x = wacc[t][0] + f4.x; o.y = wacc[t][1] + f4.y;
                o.z = wacc[t][2] + f4.z; o.w = wacc[t][3] + f4.w;
                *(float4*)&wout[b * 4096 + (m0 + n) * 64 + t * 16 + quad * 4] = o;
            }
        }
    }

    // ---- Phase 4: out = ctx @ W_out^T + b_out, written [L, B, E] ----
    // wave (sp = w&1, cq = w>>1): st in {2sp, 2sp+1}, ct in {4cq .. 4cq+3}
    {
        const int sp = w & 1;
        const int cq = w >> 1;
        bf16x8 actx[2][8];                        // afr dead -> regs reused
        #pragma unroll
        for (int st2 = 0; st2 < 2; ++st2)
            #pragma unroll
            for (int ks = 0; ks < 8; ++ks)
                actx[st2][ks] = *(const bf16x8*)&cs[(2 * sp + st2) * 16 + n][ks * 32 + quad * 8];

        #pragma unroll 2
        for (int ci = 0; ci < 4; ++ci) {
            const int ct = 4 * cq + ci;
            const u16* wr = w_out_bf + (ct * 16 + n) * 256 + quad * 8;
            f32x4 acc[2];
            acc[0] = (f32x4){0.f, 0.f, 0.f, 0.f};
            acc[1] = (f32x4){0.f, 0.f, 0.f, 0.f};
            #pragma unroll
            for (int kh = 0; kh < 2; ++kh) {
                bf16x8 bfr[4];
                #pragma unroll
                for (int k4 = 0; k4 < 4; ++k4) bfr[k4] = *(const bf16x8*)(wr + (kh * 4 + k4) * 32);
                #pragma unroll
                for (int k4 = 0; k4 < 4; ++k4) {
                    acc[0] = MFMA16(actx[0][kh * 4 + k4], bfr[k4], acc[0]);
                    acc[1] = MFMA16(actx[1][kh * 4 + k4], bfr[k4], acc[1]);
                }
            }
            float bias = bias_out[ct * 16 + n];
            #pragma unroll
            for (int st2 = 0; st2 < 2; ++st2) {
                const int orow = (2 * sp + st2) * 16 + quad * 4;
                #pragma unroll
                for (int r = 0; r < 4; ++r)
                    out[(orow + r) * 262144 + b * 256 + ct * 16 + n] = acc[st2][r] + bias;
            }
        }
    }
}

// ---------------------------------------------------------------------------
extern "C" void kernel_launch(void* const* d_in, const int* in_sizes, int n_in,
                              void* d_out, int out_size, void* d_ws, size_t ws_size,
                              hipStream_t stream) {
    const float* X     = (const float*)d_in[0];
    const int*   bidx  = (const int*)d_in[1];
    const float* w_in  = (const float*)d_in[2];
    const float* b_in  = (const float*)d_in[3];
    const float* w_out = (const float*)d_in[4];
    const float* b_out = (const float*)d_in[5];
    const int N = in_sizes[1];

    float* out  = (float*)d_out;                 // [64, 1024, 256]
    float* wout = out + 64 * 1024 * 256;         // [1024, 64, 64]

    int* starts   = (int*)d_ws;
    int* counts   = starts + 1024;
    u16* w_in_bf  = (u16*)(counts + 1024);       // 768x256 bf16
    u16* w_out_bf = w_in_bf + 196608;            // 256x256 bf16

    hipLaunchKernelGGL(prep_kernel, dim3(192), dim3(256), 0, stream,
                       bidx, N, w_in, w_out, starts, counts, w_in_bf, w_out_bf);
    hipLaunchKernelGGL(gat_kernel, dim3(1024), dim3(512), 0, stream,
                       X, b_in, b_out, starts, counts, w_in_bf, w_out_bf, out, wout);
}